// Round 2
// baseline (127.031 us; speedup 1.0000x reference)
//
#include <hip/hip_runtime.h>

// BEVPoolV2: out[v][c] = sum_{j=0..39} depth_2d[ranks_depth[v*40+j]] * feat_2d[ranks_feat[v*40+j]][c]
//   depth: 498432 fp32 scalars (+1 virtual zero row)
//   feat : 4224 rows x 64 fp32 (+1 virtual zero row)
//   ranks: 1.6M int32 each
//   out  : 40000 voxels x 64 fp32
//
// Structure: one wave per voxel, one lane per channel. Voxel id is forced
// wave-uniform via readfirstlane so all index/depth loads become scalar
// (s_load) ops; the 40 feat gathers are phase-split from the index loads so
// the compiler can keep many vector loads in flight (latency -> throughput).

#define ND_ROWS (1 * 6 * 118 * 16 * 44) // 498432
#define NF_ROWS (1 * 6 * 16 * 44)       // 4224
#define C_CH 64
#define MAXN_PTS 40
#define NVOX (200 * 200) // 40000
#define WAVES_PER_BLOCK 4

__global__ __launch_bounds__(256) void BEVPoolV2_79783312491037_kernel(
    const float* __restrict__ depth,
    const float* __restrict__ feat,
    const int* __restrict__ ranks_depth,
    const int* __restrict__ ranks_feat,
    float* __restrict__ out)
{
    const int lane = threadIdx.x & 63;
    const int wave = threadIdx.x >> 6;
    // Wave-uniform voxel id -> scalar address math -> s_load for ranks/depth.
    const int v = __builtin_amdgcn_readfirstlane(blockIdx.x * WAVES_PER_BLOCK + wave);
    const int pbase = v * MAXN_PTS;

    // Phase 1: all 40 index pairs (contiguous -> s_load_dwordx4/x8 merges)
    // and all 40 depth scalars (scattered s_load_dword), branch-free validity.
    float dv[MAXN_PTS];
    int   rfc[MAXN_PTS];
#pragma unroll
    for (int j = 0; j < MAXN_PTS; ++j) {
        const int rd = ranks_depth[pbase + j];
        const int rf = ranks_feat[pbase + j];
        const bool valid = (rd < ND_ROWS) && (rf < NF_ROWS);
        const int rdc = valid ? rd : 0;          // safe address
        rfc[j] = (rf < NF_ROWS) ? rf : 0;        // safe address
        const float d = depth[rdc];
        dv[j] = valid ? d : 0.0f;                // pad-row contributes 0
    }

    // Phase 2: 40 independent 256 B/wave L2 gathers + FMA. All addresses are
    // known before any load is consumed -> deep vmcnt pipelining.
    float acc = 0.0f;
#pragma unroll
    for (int j = 0; j < MAXN_PTS; ++j) {
        const float f = feat[rfc[j] * C_CH + lane];
        acc = fmaf(dv[j], f, acc);
    }

    // Streaming output: non-temporal so 10 MB of writes don't evict the
    // L2-resident feat/depth working set.
    __builtin_nontemporal_store(acc, &out[v * C_CH + lane]);
}

extern "C" void kernel_launch(void* const* d_in, const int* in_sizes, int n_in,
                              void* d_out, int out_size, void* d_ws, size_t ws_size,
                              hipStream_t stream)
{
    const float* depth       = (const float*)d_in[0];
    const float* feat        = (const float*)d_in[1];
    const int*   ranks_depth = (const int*)d_in[2];
    const int*   ranks_feat  = (const int*)d_in[3];
    // d_in[4] is maxn (=40), hardcoded as MAXN_PTS.
    float* out = (float*)d_out;

    const int blocks = NVOX / WAVES_PER_BLOCK; // 10000
    BEVPoolV2_79783312491037_kernel<<<blocks, 256, 0, stream>>>(
        depth, feat, ranks_depth, ranks_feat, out);
}

// Round 4
// 93.246 us; speedup vs baseline: 1.3623x; 1.3623x over previous
//
#include <hip/hip_runtime.h>

// BEVPoolV2: out[v][c] = sum_{j=0..39} depth_2d[rd[v*40+j]] * feat_2d[rf[v*40+j]][c]
//   depth: 498432 fp32 scalars (+1 virtual zero row)
//   feat : 4224 rows x 64 fp32 (+1 virtual zero row)  -> 1.08 MB, L2-resident
//   ranks: 1.6M int32 each (streamed once)
//   out  : 40000 voxels x 64 fp32 (streamed once)
//
// Structure: block = 256 threads = 16 voxels.
//   Stage:   threads 0..159 load the block's 640 (rd,rf) pairs via int4,
//            gather depth (clamped, validity folded into d), write (d,rf)
//            pairs to LDS (stride-41 padding -> conflict-free broadcast).
//   Compute: lane owns float4 of channels; 16 lanes per voxel, 4 voxels per
//            wave. Per step: ds_read_b64 (broadcast) + 1 KB/wave feat gather
//            + 4 FMAs. 40 independent steps -> deep vmcnt pipelining.

// clang native vectors (required by __builtin_nontemporal_*; HIP_vector_type is rejected)
typedef int   vint4   __attribute__((ext_vector_type(4)));
typedef float vfloat4 __attribute__((ext_vector_type(4)));

#define ND_ROWS (1 * 6 * 118 * 16 * 44) // 498432
#define NF_ROWS (1 * 6 * 16 * 44)       // 4224
#define MAXN_PTS 40
#define NVOX (200 * 200)                // 40000
#define VOX_PER_BLOCK 16
#define PAIR4_PER_BLOCK (VOX_PER_BLOCK * MAXN_PTS / 4) // 160 int4 loads
#define LDS_STRIDE 41                   // 41*8 B/voxel: odd stride -> conflict-free

__global__ __launch_bounds__(256) void BEVPoolV2_79783312491037_kernel(
    const float* __restrict__ depth,
    const vfloat4* __restrict__ feat4,  // 4224 rows x 16 float4
    const vint4* __restrict__ rd4,
    const vint4* __restrict__ rf4,
    vfloat4* __restrict__ out4)
{
    __shared__ float2 s_pair[VOX_PER_BLOCK * LDS_STRIDE]; // {d, rf-as-bits}

    const int t = threadIdx.x;

    // ---- Stage: 640 pairs for this block's 16 voxels ----
    if (t < PAIR4_PER_BLOCK) {
        const vint4 rd = __builtin_nontemporal_load(&rd4[blockIdx.x * PAIR4_PER_BLOCK + t]);
        const vint4 rf = __builtin_nontemporal_load(&rf4[blockIdx.x * PAIR4_PER_BLOCK + t]);
        const int base = t * 4;
#pragma unroll
        for (int k = 0; k < 4; ++k) {
            const int idx = base + k;
            const int g = idx / MAXN_PTS;           // voxel within block
            const int j = idx - g * MAXN_PTS;       // point within voxel
            const int rdk = rd[k], rfk = rf[k];
            const bool valid = (rdk < ND_ROWS) && (rfk < NF_ROWS);
            // clamped address -> always-safe vector gather; invalid -> d = 0
            const float dl = depth[min(rdk, ND_ROWS - 1)];
            float2 p;
            p.x = valid ? dl : 0.0f;
            p.y = __int_as_float((rfk < NF_ROWS) ? rfk : 0);
            s_pair[g * LDS_STRIDE + j] = p;
        }
    }
    __syncthreads();

    // ---- Compute: lane = (voxel g = t>>4, channel quad c4 = t&15) ----
    const int g = t >> 4;
    const int c4 = t & 15;
    const int pbase = g * LDS_STRIDE;

    vfloat4 acc = {0.0f, 0.0f, 0.0f, 0.0f};
#pragma unroll
    for (int j = 0; j < MAXN_PTS; ++j) {
        const float2 p = s_pair[pbase + j];         // ds_read_b64, broadcast x16
        const float d = p.x;
        const int rf = __float_as_int(p.y);
        const vfloat4 f = feat4[rf * 16 + c4];      // 1 KB/wave L2 gather
        acc.x = fmaf(d, f.x, acc.x);
        acc.y = fmaf(d, f.y, acc.y);
        acc.z = fmaf(d, f.z, acc.z);
        acc.w = fmaf(d, f.w, acc.w);
    }

    // voxel v = blockIdx.x*16 + g, channels c4*4.. -> out4[blockIdx.x*256 + t]
    __builtin_nontemporal_store(acc, &out4[blockIdx.x * 256 + t]);
}

extern "C" void kernel_launch(void* const* d_in, const int* in_sizes, int n_in,
                              void* d_out, int out_size, void* d_ws, size_t ws_size,
                              hipStream_t stream)
{
    const float*   depth = (const float*)d_in[0];
    const vfloat4* feat4 = (const vfloat4*)d_in[1];
    const vint4*   rd4   = (const vint4*)d_in[2];
    const vint4*   rf4   = (const vint4*)d_in[3];
    // d_in[4] is maxn (=40), hardcoded as MAXN_PTS.
    vfloat4* out4 = (vfloat4*)d_out;

    const int blocks = NVOX / VOX_PER_BLOCK; // 2500
    BEVPoolV2_79783312491037_kernel<<<blocks, 256, 0, stream>>>(
        depth, feat4, rd4, rf4, out4);
}